// Round 8
// baseline (250.659 us; speedup 1.0000x reference)
//
#include <hip/hip_runtime.h>

typedef __bf16 bf16x8 __attribute__((ext_vector_type(8)));
typedef float f32x4 __attribute__((ext_vector_type(4)));

#define BATCH 4
#define SEQ   2048
#define DIM   1024
#define NH    16
#define HD    64
#define ECF   0.18033688f   // log2(e)/8 : folds 1/sqrt(64) into exp2

__device__ __forceinline__ unsigned short f2bf(float f) {
  union { float f; unsigned u; } v; v.f = f;
  unsigned u = v.u;
  u += 0x7FFF + ((u >> 16) & 1);   // round-to-nearest-even
  return (unsigned short)(u >> 16);
}

__device__ __forceinline__ void g2lds16(const unsigned short* g, unsigned short* l) {
  __builtin_amdgcn_global_load_lds(
      (const __attribute__((address_space(1))) unsigned int*)g,
      (__attribute__((address_space(3))) unsigned int*)l, 16, 0, 0);
}

// ------------- fused cast fp32 -> bf16 (x, Wq*EC, Wk, Wv) -------------
__global__ __launch_bounds__(256) void cast_all_kernel(
    const float* __restrict__ x,  const float* __restrict__ Wq,
    const float* __restrict__ Wk, const float* __restrict__ Wv,
    unsigned short* __restrict__ xb,  unsigned short* __restrict__ wqb,
    unsigned short* __restrict__ wkb, unsigned short* __restrict__ wvb) {
  const int XG = (BATCH * SEQ * DIM) / 8;   // 1048576
  const int WG = (DIM * DIM) / 8;           // 131072
  int i = blockIdx.x * 256 + threadIdx.x;
  const float* in; unsigned short* out; float sc = 1.0f; int off;
  if (i < XG)               { in = x;  out = xb;  off = i; }
  else if (i < XG + WG)     { in = Wq; out = wqb; off = i - XG; sc = ECF; }
  else if (i < XG + 2 * WG) { in = Wk; out = wkb; off = i - XG - WG; }
  else                      { in = Wv; out = wvb; off = i - XG - 2 * WG; }
  const float4* p = (const float4*)in + (size_t)off * 2;
  float4 a = p[0], b = p[1];
  unsigned short r[8];
  r[0] = f2bf(a.x * sc); r[1] = f2bf(a.y * sc); r[2] = f2bf(a.z * sc); r[3] = f2bf(a.w * sc);
  r[4] = f2bf(b.x * sc); r[5] = f2bf(b.y * sc); r[6] = f2bf(b.z * sc); r[7] = f2bf(b.w * sc);
  *(uint4*)&out[(size_t)off * 8] = *(uint4*)r;
}

// -------- fused QKV projection GEMM: 256x128 tile, BK=64, 2-phase -----
// R13: R11 body unchanged (counted-vmcnt triple-buffer, setprio). The R11
// post-mortem showed gemm is HBM-bound on PANEL REFETCH, not schedule-bound:
// 768 blocks x (512KB A-panel + 256KB B-panel) = 576MB / 6.3TB/s = 91us
// (unique data is only 22MB -- L3-resident). Default block->XCD round-robin
// scatters the 24 blocks sharing an A-panel across 8 incoherent L2s.
// Fix = T1 XCD-chunked m-major swizzle: lid=(hw&7)*96+(hw>>3), m=lid/24 ->
// same-A blocks consecutive on one XCD (A-chunk 2MB fits 4MB L2; W 6MB L3).
__global__ __launch_bounds__(512, 1) void gemm_qkv(
    const unsigned short* __restrict__ A,
    const unsigned short* __restrict__ Wqp, const unsigned short* __restrict__ Wkp,
    const unsigned short* __restrict__ Wvp,
    const float* __restrict__ bqp, const float* __restrict__ bkp,
    const float* __restrict__ bvp,
    unsigned short* __restrict__ oq, unsigned short* __restrict__ ok,
    unsigned short* __restrict__ ov) {
  __shared__ __align__(16) unsigned short sm[3 * 24576];   // 144KB

  // ---- T1 XCD-chunked decode: 768 blocks, 8 XCDs, chunk=96, m-major ----
  const int hw  = blockIdx.x;
  const int lid = (hw & 7) * 96 + (hw >> 3);
  const int mi  = lid / 24;          // 0..31  (A-panel index)
  const int rem = lid % 24;
  const int ni  = rem / 3;           // 0..7   (B-panel index)
  const int z   = rem % 3;           // Q/K/V

  const unsigned short* W = (z == 0) ? Wqp : (z == 1) ? Wkp : Wvp;
  const float* bias        = (z == 0) ? bqp : (z == 1) ? bkp : bvp;
  unsigned short* outp     = (z == 0) ? oq  : (z == 1) ? ok  : ov;
  const float bsc          = (z == 0) ? ECF : 1.0f;
  const int mode = (z == 2) ? 1 : 0;

  const int tid  = threadIdx.x;
  const int w    = tid >> 6;
  const int lane = tid & 63;
  const int lm   = lane & 15;
  const int qd   = lane >> 4;
  const int m0 = mi * 256;
  const int n0 = ni * 128;
  const int wm = (w & 3) * 64;
  const int wn = (w >> 2) * 64;

  f32x4 acc[4][4];
#pragma unroll
  for (int i = 0; i < 4; ++i)
#pragma unroll
    for (int j = 0; j < 4; ++j) acc[i][j] = {0.f, 0.f, 0.f, 0.f};

  const int r0 = tid >> 3;
  const int sp = ((tid & 7) ^ (r0 & 7)) * 8;

#define SA(buf, t4, i) g2lds16(&A[(size_t)(m0 + r0 + 64*(i)) * DIM + (t4)*64 + sp], \
                               &sm[(buf)*24576 + (r0 + 64*(i))*64 + (tid & 7)*8])
#define SB(buf, t4, i) g2lds16(&W[(size_t)(n0 + r0 + 64*(i)) * DIM + (t4)*64 + sp], \
                               &sm[(buf)*24576 + 16384 + (r0 + 64*(i))*64 + (tid & 7)*8])
#define BARR() asm volatile("s_barrier" ::: "memory")

  const int rk = lm & 7;

  SA(0, 0, 0); SA(0, 0, 1); SA(0, 0, 2); SA(0, 0, 3); SB(0, 0, 0); SB(0, 0, 1);
  SA(1, 1, 0); SA(1, 1, 1); SA(1, 1, 2); SA(1, 1, 3); SB(1, 1, 0); SB(1, 1, 1);
  asm volatile("s_waitcnt vmcnt(6)" ::: "memory");
  BARR();

  for (int t = 0; t < DIM / 64; ++t) {
    const int cur = t % 3;
    const int nb  = (t + 2) % 3;
    const bool st = (t + 2) < DIM / 64;
    const unsigned short* Ab = &sm[cur * 24576];
    const unsigned short* Bb = &sm[cur * 24576 + 16384];

    {
      bf16x8 af[4], bfr[4];
#pragma unroll
      for (int i = 0; i < 4; ++i)
        af[i]  = *(const bf16x8*)&Ab[(wm + i * 16 + lm) * 64 + ((qd ^ rk) * 8)];
#pragma unroll
      for (int j = 0; j < 4; ++j)
        bfr[j] = *(const bf16x8*)&Bb[(wn + j * 16 + lm) * 64 + ((qd ^ rk) * 8)];
      if (st) { SA(nb, t + 2, 0); SA(nb, t + 2, 1); SA(nb, t + 2, 2); }
      BARR();
      __builtin_amdgcn_s_setprio(1);
#pragma unroll
      for (int i = 0; i < 4; ++i)
#pragma unroll
        for (int j = 0; j < 4; ++j)
          acc[i][j] = __builtin_amdgcn_mfma_f32_16x16x32_bf16(af[i], bfr[j], acc[i][j], 0, 0, 0);
      __builtin_amdgcn_s_setprio(0);
      BARR();
    }
    {
      bf16x8 af[4], bfr[4];
#pragma unroll
      for (int i = 0; i < 4; ++i)
        af[i]  = *(const bf16x8*)&Ab[(wm + i * 16 + lm) * 64 + (((4 + qd) ^ rk) * 8)];
#pragma unroll
      for (int j = 0; j < 4; ++j)
        bfr[j] = *(const bf16x8*)&Bb[(wn + j * 16 + lm) * 64 + (((4 + qd) ^ rk) * 8)];
      if (st) { SA(nb, t + 2, 3); SB(nb, t + 2, 0); SB(nb, t + 2, 1); }
      BARR();
      __builtin_amdgcn_s_setprio(1);
#pragma unroll
      for (int i = 0; i < 4; ++i)
#pragma unroll
        for (int j = 0; j < 4; ++j)
          acc[i][j] = __builtin_amdgcn_mfma_f32_16x16x32_bf16(af[i], bfr[j], acc[i][j], 0, 0, 0);
      __builtin_amdgcn_s_setprio(0);
      if (st) asm volatile("s_waitcnt vmcnt(6)" ::: "memory");
      else    asm volatile("s_waitcnt vmcnt(0)" ::: "memory");
      BARR();
    }
  }
#undef SA
#undef SB
#undef BARR

#pragma unroll
  for (int j = 0; j < 4; ++j) {
    int col = n0 + wn + j * 16 + lm;
    float bb = bias[col] * bsc;
    int h = col >> 6, hd = col & 63;
#pragma unroll
    for (int i = 0; i < 4; ++i) {
      int rowb = m0 + wm + i * 16 + qd * 4;
      int b = rowb >> 11, s = rowb & 2047;
      if (mode == 0) {
#pragma unroll
        for (int r = 0; r < 4; ++r) {
          float v = acc[i][j][r] + bb;
          outp[((size_t)(b * NH + h) * SEQ + (s + r)) * HD + hd] = f2bf(v);
        }
      } else {
        unsigned short pk[4];
#pragma unroll
        for (int r = 0; r < 4; ++r) pk[r] = f2bf(acc[i][j][r] + bb);
        size_t idx = ((size_t)(b * NH + h) * HD + hd) * SEQ + s;
        *(uint2*)&outp[idx] = *(uint2*)pk;
      }
    }
  }
}

// ---------------- flash attention: 2 waves, 64 q-rows/wave -----------
// Best-measured variant (R0/R11-run). R6-R12 established ~96-99us as this
// op's structural floor across occupancy/split-K/phase/barrier-free variants.
__global__ __launch_bounds__(128, 2) void flash_kernel(
    const unsigned short* __restrict__ Qw, const unsigned short* __restrict__ Kw,
    const unsigned short* __restrict__ Vw, float* __restrict__ out) {
  __shared__ unsigned short Ks2[2 * 64 * 32];   // [hd_half][key][32] swizzled
  __shared__ unsigned short Vs2[2 * 64 * 32];   // [key_half][hd][32] swizzled
  __shared__ unsigned short Ps[128 * 64];       // [qrow][key] chunk-swizzled
  __shared__ float Ls[128];

  const int tid  = threadIdx.x;   // 0..127
  const int w    = tid >> 6;      // wave 0..1
  const int lane = tid & 63;
  const int lm   = lane & 15;
  const int qd   = lane >> 4;
  const int bh   = blockIdx.y;
  const int q0   = blockIdx.x * 128;

  const unsigned short* Qbase = Qw + (size_t)bh * (SEQ * HD);
  const unsigned short* Kbase = Kw + (size_t)bh * (SEQ * HD);
  const unsigned short* Vbase = Vw + (size_t)bh * (HD * SEQ);

  // Q fragments in registers: 64 rows per wave (4 groups of 16)
  bf16x8 qf[4][2];
#pragma unroll
  for (int g = 0; g < 4; ++g)
#pragma unroll
    for (int h = 0; h < 2; ++h)
      qf[g][h] = *(const bf16x8*)&Qbase[(size_t)(q0 + w * 64 + g * 16 + lm) * HD + h * 32 + qd * 8];

  const f32x4 zero = {0.f, 0.f, 0.f, 0.f};
  f32x4 o[4][4];
#pragma unroll
  for (int g = 0; g < 4; ++g)
#pragma unroll
    for (int jn = 0; jn < 4; ++jn) o[g][jn] = zero;
  float psg[4] = {0.f, 0.f, 0.f, 0.f};

  // staging: 256 16B-chunks per tensor-half pair; thread t fills chunks t, t+128
  const int c0 = tid, c1 = tid + 128;
  const int r0 = c0 >> 2, p0s = ((c0 & 3) ^ ((c0 >> 3) & 3)) * 8;
  const int r1 = c1 >> 2, p1s = ((c1 & 3) ^ ((c1 >> 3) & 3)) * 8;

  const int cs  = (qd ^ ((lm >> 1) & 3)) * 8;   // K/V swizzled read chunk
  const int pk_key = lm & 7;                     // Ps swizzle key

  for (int kt = 0; kt < SEQ / 64; ++kt) {
    const int k0 = kt * 64;
    __syncthreads();
    g2lds16(&Kbase[(size_t)(k0 + r0) * HD + p0s],      &Ks2[(size_t)c0 * 8]);
    g2lds16(&Kbase[(size_t)(k0 + r1) * HD + p1s],      &Ks2[(size_t)c1 * 8]);
    g2lds16(&Kbase[(size_t)(k0 + r0) * HD + 32 + p0s], &Ks2[2048 + (size_t)c0 * 8]);
    g2lds16(&Kbase[(size_t)(k0 + r1) * HD + 32 + p1s], &Ks2[2048 + (size_t)c1 * 8]);
    g2lds16(&Vbase[(size_t)r0 * SEQ + k0 + p0s],       &Vs2[(size_t)c0 * 8]);
    g2lds16(&Vbase[(size_t)r1 * SEQ + k0 + p1s],       &Vs2[(size_t)c1 * 8]);
    g2lds16(&Vbase[(size_t)r0 * SEQ + k0 + 32 + p0s],  &Vs2[2048 + (size_t)c0 * 8]);
    g2lds16(&Vbase[(size_t)r1 * SEQ + k0 + 32 + p1s],  &Vs2[2048 + (size_t)c1 * 8]);
    __syncthreads();

    // S^T = K Q^T : rows key=jk*16+qd*4+r, cols qrow=g*16+lm
#pragma unroll
    for (int jk = 0; jk < 4; ++jk) {
      bf16x8 kf0 = *(const bf16x8*)&Ks2[(jk * 16 + lm) * 32 + cs];
      bf16x8 kf1 = *(const bf16x8*)&Ks2[2048 + (jk * 16 + lm) * 32 + cs];
      f32x4 st[4];
#pragma unroll
      for (int g = 0; g < 4; ++g) {
        st[g] = __builtin_amdgcn_mfma_f32_16x16x32_bf16(kf0, qf[g][0], zero, 0, 0, 0);
        st[g] = __builtin_amdgcn_mfma_f32_16x16x32_bf16(kf1, qf[g][1], st[g], 0, 0, 0);
      }
#pragma unroll
      for (int g = 0; g < 4; ++g) {
        float p0 = __builtin_amdgcn_exp2f(st[g][0]);
        float p1 = __builtin_amdgcn_exp2f(st[g][1]);
        float p2 = __builtin_amdgcn_exp2f(st[g][2]);
        float p3 = __builtin_amdgcn_exp2f(st[g][3]);
        psg[g] += (p0 + p1) + (p2 + p3);
        uint2 pk;
        pk.x = __builtin_amdgcn_perm(__float_as_uint(p1), __float_as_uint(p0), 0x07060302);
        pk.y = __builtin_amdgcn_perm(__float_as_uint(p3), __float_as_uint(p2), 0x07060302);
        // logical chunk 2jk+(qd>>1), swizzled by row&7 = lm&7
        int sw = (2 * jk + (qd >> 1)) ^ pk_key;
        *(uint2*)&Ps[(w * 64 + g * 16 + lm) * 64 + sw * 8 + (qd & 1) * 4] = pk;
      }
    }

    // same-wave LDS RAW (wave w only touches its own 64 Ps rows)
    asm volatile("s_waitcnt lgkmcnt(0)" ::: "memory");

    // O += P V
#pragma unroll
    for (int h2 = 0; h2 < 2; ++h2) {
      bf16x8 pf[4];
#pragma unroll
      for (int g = 0; g < 4; ++g) {
        int sw = (h2 * 4 + qd) ^ pk_key;
        pf[g] = *(const bf16x8*)&Ps[(w * 64 + g * 16 + lm) * 64 + sw * 8];
      }
#pragma unroll
      for (int jn = 0; jn < 4; ++jn) {
        bf16x8 vf = *(const bf16x8*)&Vs2[h2 * 2048 + (jn * 16 + lm) * 32 + cs];
#pragma unroll
        for (int g = 0; g < 4; ++g)
          o[g][jn] = __builtin_amdgcn_mfma_f32_16x16x32_bf16(pf[g], vf, o[g][jn], 0, 0, 0);
      }
    }
  }

  // final row-sum reduce (over the 4 qd lane-groups) and normalize
#pragma unroll
  for (int g = 0; g < 4; ++g) {
    float l = psg[g];
    l += __shfl_xor(l, 16); l += __shfl_xor(l, 32);
    if (qd == 0) Ls[w * 64 + g * 16 + lm] = l;
  }
  asm volatile("s_waitcnt lgkmcnt(0)" ::: "memory");

  const int b = bh >> 4, hh = bh & 15;
#pragma unroll
  for (int g = 0; g < 4; ++g)
#pragma unroll
    for (int r = 0; r < 4; ++r) {
      float inv = 1.0f / Ls[w * 64 + g * 16 + qd * 4 + r];
      int qrow = q0 + w * 64 + g * 16 + qd * 4 + r;
#pragma unroll
      for (int jn = 0; jn < 4; ++jn)
        out[(size_t)(b * SEQ + qrow) * DIM + hh * HD + jn * 16 + lm] = o[g][jn][r] * inv;
    }
}

extern "C" void kernel_launch(void* const* d_in, const int* in_sizes, int n_in,
                              void* d_out, int out_size, void* d_ws, size_t ws_size,
                              hipStream_t stream) {
  const float* x  = (const float*)d_in[0];
  const float* Wq = (const float*)d_in[1];
  const float* bq = (const float*)d_in[2];
  const float* Wk = (const float*)d_in[3];
  const float* bk = (const float*)d_in[4];
  const float* Wv = (const float*)d_in[5];
  const float* bv = (const float*)d_in[6];
  float* out = (float*)d_out;

  unsigned short* ws = (unsigned short*)d_ws;
  const size_t XE = (size_t)BATCH * SEQ * DIM;   // 8388608
  const size_t WE = (size_t)DIM * DIM;           // 1048576
  unsigned short* xb  = ws;
  unsigned short* wqb = xb + XE;
  unsigned short* wkb = wqb + WE;
  unsigned short* wvb = wkb + WE;
  unsigned short* qb  = wvb + WE;
  unsigned short* kb  = qb + XE;
  unsigned short* vb  = kb + XE;

  const int total_groups = (int)(XE / 8 + 3 * (WE / 8));   // 1441792
  cast_all_kernel<<<total_groups / 256, 256, 0, stream>>>(
      x, Wq, Wk, Wv, xb, wqb, wkb, wvb);

  gemm_qkv<<<768, 512, 0, stream>>>(xb, wqb, wkb, wvb, bq, bk, bv, qb, kb, vb);

  dim3 fg(SEQ / 128, BATCH * NH);
  flash_kernel<<<fg, 128, 0, stream>>>(qb, kb, vb, out);
}

// Round 9
// 238.395 us; speedup vs baseline: 1.0514x; 1.0514x over previous
//
#include <hip/hip_runtime.h>

typedef __bf16 bf16x8 __attribute__((ext_vector_type(8)));
typedef float f32x4 __attribute__((ext_vector_type(4)));

#define BATCH 4
#define SEQ   2048
#define DIM   1024
#define NH    16
#define HD    64
#define ECF   0.18033688f   // log2(e)/8 : folds 1/sqrt(64) into exp2

__device__ __forceinline__ unsigned short f2bf(float f) {
  union { float f; unsigned u; } v; v.f = f;
  unsigned u = v.u;
  u += 0x7FFF + ((u >> 16) & 1);   // round-to-nearest-even
  return (unsigned short)(u >> 16);
}

__device__ __forceinline__ void g2lds16(const unsigned short* g, unsigned short* l) {
  __builtin_amdgcn_global_load_lds(
      (const __attribute__((address_space(1))) unsigned int*)g,
      (__attribute__((address_space(3))) unsigned int*)l, 16, 0, 0);
}

// ------------- fused cast fp32 -> bf16 (x, Wq*EC, Wk, Wv) -------------
__global__ __launch_bounds__(256) void cast_all_kernel(
    const float* __restrict__ x,  const float* __restrict__ Wq,
    const float* __restrict__ Wk, const float* __restrict__ Wv,
    unsigned short* __restrict__ xb,  unsigned short* __restrict__ wqb,
    unsigned short* __restrict__ wkb, unsigned short* __restrict__ wvb) {
  const int XG = (BATCH * SEQ * DIM) / 8;   // 1048576
  const int WG = (DIM * DIM) / 8;           // 131072
  int i = blockIdx.x * 256 + threadIdx.x;
  const float* in; unsigned short* out; float sc = 1.0f; int off;
  if (i < XG)               { in = x;  out = xb;  off = i; }
  else if (i < XG + WG)     { in = Wq; out = wqb; off = i - XG; sc = ECF; }
  else if (i < XG + 2 * WG) { in = Wk; out = wkb; off = i - XG - WG; }
  else                      { in = Wv; out = wvb; off = i - XG - 2 * WG; }
  const float4* p = (const float4*)in + (size_t)off * 2;
  float4 a = p[0], b = p[1];
  unsigned short r[8];
  r[0] = f2bf(a.x * sc); r[1] = f2bf(a.y * sc); r[2] = f2bf(a.z * sc); r[3] = f2bf(a.w * sc);
  r[4] = f2bf(b.x * sc); r[5] = f2bf(b.y * sc); r[6] = f2bf(b.z * sc); r[7] = f2bf(b.w * sc);
  *(uint4*)&out[(size_t)off * 8] = *(uint4*)r;
}

// -------- fused QKV projection GEMM: 256x128 tile, BK=64 --------------
// R14: grid mapping reverted to (32,8,3) -- post-mortem showed it was
// already A-panel-XCD-local (XCD = mi%8 since gridDim.x%8==0) and R13's
// m-major remap broke B/z L2 locality (+8us). Inner loop restructured to
// attack the m233 stall (gemm runs ~3.5x over its 23us DS-pipe bound):
// ONE barrier-pair per K-tile (was 2): prefetch ALL 16 fragments (both
// kk-halves, 64 VGPR) -> BAR -> setprio + 32-MFMA cluster -> counted
// vmcnt(6) -> BAR. Half the barriers, double the MFMA per cluster; the
// counted vmcnt keeps t+2's 6 staging loads in flight across the barrier
// (T4) so only t+1's are drained. Triple-buffer LDS 144KB, 1 block/CU.
__global__ __launch_bounds__(512, 1) void gemm_qkv(
    const unsigned short* __restrict__ A,
    const unsigned short* __restrict__ Wqp, const unsigned short* __restrict__ Wkp,
    const unsigned short* __restrict__ Wvp,
    const float* __restrict__ bqp, const float* __restrict__ bkp,
    const float* __restrict__ bvp,
    unsigned short* __restrict__ oq, unsigned short* __restrict__ ok,
    unsigned short* __restrict__ ov) {
  __shared__ __align__(16) unsigned short sm[3 * 24576];   // 144KB

  const int z = blockIdx.z;
  const unsigned short* W = (z == 0) ? Wqp : (z == 1) ? Wkp : Wvp;
  const float* bias        = (z == 0) ? bqp : (z == 1) ? bkp : bvp;
  unsigned short* outp     = (z == 0) ? oq  : (z == 1) ? ok  : ov;
  const float bsc          = (z == 0) ? ECF : 1.0f;
  const int mode = (z == 2) ? 1 : 0;

  const int tid  = threadIdx.x;
  const int w    = tid >> 6;
  const int lane = tid & 63;
  const int lm   = lane & 15;
  const int qd   = lane >> 4;
  const int m0 = blockIdx.x * 256;
  const int n0 = blockIdx.y * 128;
  const int wm = (w & 3) * 64;
  const int wn = (w >> 2) * 64;

  f32x4 acc[4][4];
#pragma unroll
  for (int i = 0; i < 4; ++i)
#pragma unroll
    for (int j = 0; j < 4; ++j) acc[i][j] = {0.f, 0.f, 0.f, 0.f};

  const int r0 = tid >> 3;
  const int sp = ((tid & 7) ^ (r0 & 7)) * 8;

#define SA(buf, t4, i) g2lds16(&A[(size_t)(m0 + r0 + 64*(i)) * DIM + (t4)*64 + sp], \
                               &sm[(buf)*24576 + (r0 + 64*(i))*64 + (tid & 7)*8])
#define SB(buf, t4, i) g2lds16(&W[(size_t)(n0 + r0 + 64*(i)) * DIM + (t4)*64 + sp], \
                               &sm[(buf)*24576 + 16384 + (r0 + 64*(i))*64 + (tid & 7)*8])
#define BARR() asm volatile("s_barrier" ::: "memory")

  const int rk = lm & 7;

  // prologue: tiles 0,1 fully staged (12 loads); wait tile0's 6 landed
  SA(0, 0, 0); SA(0, 0, 1); SA(0, 0, 2); SA(0, 0, 3); SB(0, 0, 0); SB(0, 0, 1);
  SA(1, 1, 0); SA(1, 1, 1); SA(1, 1, 2); SA(1, 1, 3); SB(1, 1, 0); SB(1, 1, 1);
  asm volatile("s_waitcnt vmcnt(6)" ::: "memory");
  BARR();

  for (int t = 0; t < DIM / 64; ++t) {          // 16 K-tiles
    const int cur = t % 3;
    const int nb  = (t + 2) % 3;
    const bool st = (t + 2) < DIM / 64;
    const unsigned short* Ab = &sm[cur * 24576];
    const unsigned short* Bb = &sm[cur * 24576 + 16384];

    // ---- prefetch ALL fragments for the whole K-tile (both kk halves) --
    bf16x8 af0[4], af1[4], bf0[4], bf1[4];
#pragma unroll
    for (int i = 0; i < 4; ++i) {
      af0[i] = *(const bf16x8*)&Ab[(wm + i * 16 + lm) * 64 + ((qd ^ rk) * 8)];
      af1[i] = *(const bf16x8*)&Ab[(wm + i * 16 + lm) * 64 + (((4 + qd) ^ rk) * 8)];
    }
#pragma unroll
    for (int j = 0; j < 4; ++j) {
      bf0[j] = *(const bf16x8*)&Bb[(wn + j * 16 + lm) * 64 + ((qd ^ rk) * 8)];
      bf1[j] = *(const bf16x8*)&Bb[(wn + j * 16 + lm) * 64 + (((4 + qd) ^ rk) * 8)];
    }
    // ---- stage tile t+2 (6 loads; stays in flight across the barrier) --
    if (st) { SA(nb, t + 2, 0); SA(nb, t + 2, 1); SA(nb, t + 2, 2);
              SA(nb, t + 2, 3); SB(nb, t + 2, 0); SB(nb, t + 2, 1); }
    BARR();
    // ---- single 32-MFMA cluster ----
    __builtin_amdgcn_s_setprio(1);
#pragma unroll
    for (int i = 0; i < 4; ++i)
#pragma unroll
      for (int j = 0; j < 4; ++j)
        acc[i][j] = __builtin_amdgcn_mfma_f32_16x16x32_bf16(af0[i], bf0[j], acc[i][j], 0, 0, 0);
#pragma unroll
    for (int i = 0; i < 4; ++i)
#pragma unroll
      for (int j = 0; j < 4; ++j)
        acc[i][j] = __builtin_amdgcn_mfma_f32_16x16x32_bf16(af1[i], bf1[j], acc[i][j], 0, 0, 0);
    __builtin_amdgcn_s_setprio(0);
    // counted drain: wait tile t+1 landed, keep t+2's 6 loads in flight
    if (st) asm volatile("s_waitcnt vmcnt(6)" ::: "memory");
    else    asm volatile("s_waitcnt vmcnt(0)" ::: "memory");
    BARR();
  }
#undef SA
#undef SB
#undef BARR

  // epilogue (same 64x64 wave-tile as the proven kernel)
#pragma unroll
  for (int j = 0; j < 4; ++j) {
    int col = n0 + wn + j * 16 + lm;
    float bb = bias[col] * bsc;
    int h = col >> 6, hd = col & 63;
#pragma unroll
    for (int i = 0; i < 4; ++i) {
      int rowb = m0 + wm + i * 16 + qd * 4;
      int b = rowb >> 11, s = rowb & 2047;
      if (mode == 0) {
#pragma unroll
        for (int r = 0; r < 4; ++r) {
          float v = acc[i][j][r] + bb;
          outp[((size_t)(b * NH + h) * SEQ + (s + r)) * HD + hd] = f2bf(v);
        }
      } else {
        unsigned short pk[4];
#pragma unroll
        for (int r = 0; r < 4; ++r) pk[r] = f2bf(acc[i][j][r] + bb);
        size_t idx = ((size_t)(b * NH + h) * HD + hd) * SEQ + s;
        *(uint2*)&outp[idx] = *(uint2*)pk;
      }
    }
  }
}

// ---------------- flash attention: 2 waves, 64 q-rows/wave -----------
// Best-measured variant (95us floor across 7 structural variants, R6-R12).
__global__ __launch_bounds__(128, 2) void flash_kernel(
    const unsigned short* __restrict__ Qw, const unsigned short* __restrict__ Kw,
    const unsigned short* __restrict__ Vw, float* __restrict__ out) {
  __shared__ unsigned short Ks2[2 * 64 * 32];   // [hd_half][key][32] swizzled
  __shared__ unsigned short Vs2[2 * 64 * 32];   // [key_half][hd][32] swizzled
  __shared__ unsigned short Ps[128 * 64];       // [qrow][key] chunk-swizzled
  __shared__ float Ls[128];

  const int tid  = threadIdx.x;   // 0..127
  const int w    = tid >> 6;      // wave 0..1
  const int lane = tid & 63;
  const int lm   = lane & 15;
  const int qd   = lane >> 4;
  const int bh   = blockIdx.y;
  const int q0   = blockIdx.x * 128;

  const unsigned short* Qbase = Qw + (size_t)bh * (SEQ * HD);
  const unsigned short* Kbase = Kw + (size_t)bh * (SEQ * HD);
  const unsigned short* Vbase = Vw + (size_t)bh * (HD * SEQ);

  // Q fragments in registers: 64 rows per wave (4 groups of 16)
  bf16x8 qf[4][2];
#pragma unroll
  for (int g = 0; g < 4; ++g)
#pragma unroll
    for (int h = 0; h < 2; ++h)
      qf[g][h] = *(const bf16x8*)&Qbase[(size_t)(q0 + w * 64 + g * 16 + lm) * HD + h * 32 + qd * 8];

  const f32x4 zero = {0.f, 0.f, 0.f, 0.f};
  f32x4 o[4][4];
#pragma unroll
  for (int g = 0; g < 4; ++g)
#pragma unroll
    for (int jn = 0; jn < 4; ++jn) o[g][jn] = zero;
  float psg[4] = {0.f, 0.f, 0.f, 0.f};

  // staging: 256 16B-chunks per tensor-half pair; thread t fills chunks t, t+128
  const int c0 = tid, c1 = tid + 128;
  const int r0 = c0 >> 2, p0s = ((c0 & 3) ^ ((c0 >> 3) & 3)) * 8;
  const int r1 = c1 >> 2, p1s = ((c1 & 3) ^ ((c1 >> 3) & 3)) * 8;

  const int cs  = (qd ^ ((lm >> 1) & 3)) * 8;   // K/V swizzled read chunk
  const int pk_key = lm & 7;                     // Ps swizzle key

  for (int kt = 0; kt < SEQ / 64; ++kt) {
    const int k0 = kt * 64;
    __syncthreads();
    g2lds16(&Kbase[(size_t)(k0 + r0) * HD + p0s],      &Ks2[(size_t)c0 * 8]);
    g2lds16(&Kbase[(size_t)(k0 + r1) * HD + p1s],      &Ks2[(size_t)c1 * 8]);
    g2lds16(&Kbase[(size_t)(k0 + r0) * HD + 32 + p0s], &Ks2[2048 + (size_t)c0 * 8]);
    g2lds16(&Kbase[(size_t)(k0 + r1) * HD + 32 + p1s], &Ks2[2048 + (size_t)c1 * 8]);
    g2lds16(&Vbase[(size_t)r0 * SEQ + k0 + p0s],       &Vs2[(size_t)c0 * 8]);
    g2lds16(&Vbase[(size_t)r1 * SEQ + k0 + p1s],       &Vs2[(size_t)c1 * 8]);
    g2lds16(&Vbase[(size_t)r0 * SEQ + k0 + 32 + p0s],  &Vs2[2048 + (size_t)c0 * 8]);
    g2lds16(&Vbase[(size_t)r1 * SEQ + k0 + 32 + p1s],  &Vs2[2048 + (size_t)c1 * 8]);
    __syncthreads();

    // S^T = K Q^T : rows key=jk*16+qd*4+r, cols qrow=g*16+lm
#pragma unroll
    for (int jk = 0; jk < 4; ++jk) {
      bf16x8 kf0 = *(const bf16x8*)&Ks2[(jk * 16 + lm) * 32 + cs];
      bf16x8 kf1 = *(const bf16x8*)&Ks2[2048 + (jk * 16 + lm) * 32 + cs];
      f32x4 st[4];
#pragma unroll
      for (int g = 0; g < 4; ++g) {
        st[g] = __builtin_amdgcn_mfma_f32_16x16x32_bf16(kf0, qf[g][0], zero, 0, 0, 0);
        st[g] = __builtin_amdgcn_mfma_f32_16x16x32_bf16(kf1, qf[g][1], st[g], 0, 0, 0);
      }
#pragma unroll
      for (int g = 0; g < 4; ++g) {
        float p0 = __builtin_amdgcn_exp2f(st[g][0]);
        float p1 = __builtin_amdgcn_exp2f(st[g][1]);
        float p2 = __builtin_amdgcn_exp2f(st[g][2]);
        float p3 = __builtin_amdgcn_exp2f(st[g][3]);
        psg[g] += (p0 + p1) + (p2 + p3);
        uint2 pk;
        pk.x = __builtin_amdgcn_perm(__float_as_uint(p1), __float_as_uint(p0), 0x07060302);
        pk.y = __builtin_amdgcn_perm(__float_as_uint(p3), __float_as_uint(p2), 0x07060302);
        // logical chunk 2jk+(qd>>1), swizzled by row&7 = lm&7
        int sw = (2 * jk + (qd >> 1)) ^ pk_key;
        *(uint2*)&Ps[(w * 64 + g * 16 + lm) * 64 + sw * 8 + (qd & 1) * 4] = pk;
      }
    }

    // same-wave LDS RAW (wave w only touches its own 64 Ps rows)
    asm volatile("s_waitcnt lgkmcnt(0)" ::: "memory");

    // O += P V
#pragma unroll
    for (int h2 = 0; h2 < 2; ++h2) {
      bf16x8 pf[4];
#pragma unroll
      for (int g = 0; g < 4; ++g) {
        int sw = (h2 * 4 + qd) ^ pk_key;
        pf[g] = *(const bf16x8*)&Ps[(w * 64 + g * 16 + lm) * 64 + sw * 8];
      }
#pragma unroll
      for (int jn = 0; jn < 4; ++jn) {
        bf16x8 vf = *(const bf16x8*)&Vs2[h2 * 2048 + (jn * 16 + lm) * 32 + cs];
#pragma unroll
        for (int g = 0; g < 4; ++g)
          o[g][jn] = __builtin_amdgcn_mfma_f32_16x16x32_bf16(pf[g], vf, o[g][jn], 0, 0, 0);
      }
    }
  }

  // final row-sum reduce (over the 4 qd lane-groups) and normalize
#pragma unroll
  for (int g = 0; g < 4; ++g) {
    float l = psg[g];
    l += __shfl_xor(l, 16); l += __shfl_xor(l, 32);
    if (qd == 0) Ls[w * 64 + g * 16 + lm] = l;
  }
  asm volatile("s_waitcnt lgkmcnt(0)" ::: "memory");

  const int b = bh >> 4, hh = bh & 15;
#pragma unroll
  for (int g = 0; g < 4; ++g)
#pragma unroll
    for (int r = 0; r < 4; ++r) {
      float inv = 1.0f / Ls[w * 64 + g * 16 + qd * 4 + r];
      int qrow = q0 + w * 64 + g * 16 + qd * 4 + r;
#pragma unroll
      for (int jn = 0; jn < 4; ++jn)
        out[(size_t)(b * SEQ + qrow) * DIM + hh * HD + jn * 16 + lm] = o[g][jn][r] * inv;
    }
}

extern "C" void kernel_launch(void* const* d_in, const int* in_sizes, int n_in,
                              void* d_out, int out_size, void* d_ws, size_t ws_size,
                              hipStream_t stream) {
  const float* x  = (const float*)d_in[0];
  const float* Wq = (const float*)d_in[1];
  const float* bq = (const float*)d_in[2];
  const float* Wk = (const float*)d_in[3];
  const float* bk = (const float*)d_in[4];
  const float* Wv = (const float*)d_in[5];
  const float* bv = (const float*)d_in[6];
  float* out = (float*)d_out;

  unsigned short* ws = (unsigned short*)d_ws;
  const size_t XE = (size_t)BATCH * SEQ * DIM;   // 8388608
  const size_t WE = (size_t)DIM * DIM;           // 1048576
  unsigned short* xb  = ws;
  unsigned short* wqb = xb + XE;
  unsigned short* wkb = wqb + WE;
  unsigned short* wvb = wkb + WE;
  unsigned short* qb  = wvb + WE;
  unsigned short* kb  = qb + XE;
  unsigned short* vb  = kb + XE;

  const int total_groups = (int)(XE / 8 + 3 * (WE / 8));   // 1441792
  cast_all_kernel<<<total_groups / 256, 256, 0, stream>>>(
      x, Wq, Wk, Wv, xb, wqb, wkb, wvb);

  dim3 gg(32, 8, 3);
  gemm_qkv<<<gg, 512, 0, stream>>>(xb, wqb, wkb, wvb, bq, bk, bv, qb, kb, vb);

  dim3 fg(SEQ / 128, BATCH * NH);
  flash_kernel<<<fg, 128, 0, stream>>>(qb, kb, vb, out);
}